// Round 3
// baseline (222.728 us; speedup 1.0000x reference)
//
#include <hip/hip_runtime.h>

#define NLAYERS 4

// tanh(a) = 1 - 2/(exp2(a*2*log2e)+1); saturates to +-1 for |a| large.
// mul + v_exp + add + v_rcp + fma = 5 VALU ops, abs err ~1e-6 (thr 6.6e-2).
__device__ __forceinline__ float ftanh(float a) {
    float e = __builtin_amdgcn_exp2f(a * 2.8853900817779268f);  // exp(2a)
    return fmaf(-2.0f, __builtin_amdgcn_rcpf(e + 1.0f), 1.0f);
}

__global__ __launch_bounds__(256) void fraud_fused(
    const float4* __restrict__ x4,
    const float* __restrict__ Ws, const float* __restrict__ bs,
    const float* __restrict__ scales, const float* __restrict__ shifts,
    const float* __restrict__ Wf, const float* __restrict__ bf,
    float4* __restrict__ out4, int nquad)
{
    // Uniform-address param loads -> scalar (s_load) hoisted before the loop.
    float w[NLAYERS][2][2], b[NLAYERS][2], s[NLAYERS][2], t[NLAYERS][2];
#pragma unroll
    for (int l = 0; l < NLAYERS; ++l) {
        w[l][0][0] = Ws[l * 4 + 0];
        w[l][0][1] = Ws[l * 4 + 1];
        w[l][1][0] = Ws[l * 4 + 2];
        w[l][1][1] = Ws[l * 4 + 3];
        b[l][0] = bs[l * 2 + 0];
        b[l][1] = bs[l * 2 + 1];
        s[l][0] = scales[l * 2 + 0];
        s[l][1] = scales[l * 2 + 1];
        t[l][0] = shifts[l * 2 + 0];
        t[l][1] = shifts[l * 2 + 1];
    }
    float wf0 = Wf[0], wf1 = Wf[1], bfv = bf[0];

    int stride = gridDim.x * blockDim.x;
    for (int i = blockIdx.x * blockDim.x + threadIdx.x; i < nquad; i += stride) {
        // 4 rows per thread: two adjacent float4 loads, one float4 store.
        float4 va = x4[2 * i];
        float4 vb = x4[2 * i + 1];
        float h0[4] = {va.x, va.z, vb.x, vb.z};
        float h1[4] = {va.y, va.w, vb.y, vb.w};
#pragma unroll
        for (int l = 0; l < NLAYERS; ++l) {
#pragma unroll
            for (int r = 0; r < 4; ++r) {
                float a0 = fmaf(w[l][0][0], h0[r], fmaf(w[l][0][1], h1[r], b[l][0]));
                float a1 = fmaf(w[l][1][0], h0[r], fmaf(w[l][1][1], h1[r], b[l][1]));
                h0[r] = fmaf(ftanh(a0), s[l][0], t[l][0]);
                h1[r] = fmaf(ftanh(a1), s[l][1], t[l][1]);
            }
        }
        float4 o;
        o.x = fmaf(wf0, h0[0], fmaf(wf1, h1[0], bfv));
        o.y = fmaf(wf0, h0[1], fmaf(wf1, h1[1], bfv));
        o.z = fmaf(wf0, h0[2], fmaf(wf1, h1[2], bfv));
        o.w = fmaf(wf0, h0[3], fmaf(wf1, h1[3], bfv));
        out4[i] = o;
    }
}

extern "C" void kernel_launch(void* const* d_in, const int* in_sizes, int n_in,
                              void* d_out, int out_size, void* d_ws, size_t ws_size,
                              hipStream_t stream) {
    const float4* x4      = (const float4*)d_in[0];
    const float*  Ws      = (const float*)d_in[1];
    const float*  bs      = (const float*)d_in[2];
    const float*  scales  = (const float*)d_in[3];
    const float*  shifts  = (const float*)d_in[4];
    const float*  Wf      = (const float*)d_in[5];
    const float*  bf      = (const float*)d_in[6];
    float4* out4          = (float4*)d_out;

    int nquad = in_sizes[0] / 8;  // 4 rows (8 floats of x) per thread-iter
    int threads = 256;
    int blocks = 4096;  // grid-stride: nquad=2.097M -> 2 iters/thread
    fraud_fused<<<blocks, threads, 0, stream>>>(x4, Ws, bs, scales, shifts,
                                                Wf, bf, out4, nquad);
}